// Round 3
// baseline (294.514 us; speedup 1.0000x reference)
//
#include <hip/hip_runtime.h>
#include <stdint.h>

#define OUT_N 11008
#define IN_K  4096
#define BATCH 32
#define SEGS  16
#define KSEG  (IN_K / SEGS)   // 256 k per block
#define NSTEP (KSEG / 32)     // 8 pipeline steps of k=32
#define OPB   64              // outputs per block (4 waves x 16 rows)
#define XSTR  264             // xs row stride (shorts): verified 0 conflicts
#define TOT   (BATCH * OUT_N)

typedef __attribute__((ext_vector_type(8))) short short8;
typedef __attribute__((ext_vector_type(4))) float float4v;
typedef __attribute__((ext_vector_type(4))) int int4v;

// fp32 -> bf16 RNE
__device__ __forceinline__ unsigned short f2bf(float f) {
    unsigned u = __builtin_bit_cast(unsigned, f);
    unsigned r = u + 0x7FFFu + ((u >> 16) & 1u);
    return (unsigned short)(r >> 16);
}

// pack two fp32 (exact {-1,0,1}) into two bf16 by mantissa truncation
__device__ __forceinline__ unsigned pkbf16(float fhi, float flo) {
    return __builtin_amdgcn_perm(__builtin_bit_cast(unsigned, fhi),
                                 __builtin_bit_cast(unsigned, flo),
                                 0x07060302u);
}

// async global->LDS DMA: 16 B per lane, lane L lands at lds_base + L*16.
// aux=2 = NT (no-allocate: caches are poison-dirty from the harness fill).
typedef const __attribute__((address_space(1))) int* gas_t;
typedef __attribute__((address_space(3))) int* las_t;
__device__ __forceinline__ void gll16(const int* g, int* l) {
    __builtin_amdgcn_global_load_lds((gas_t)g, (las_t)l, 16, 0, 2);
}

// R3 = CALIBRATION PROBE. Kernel body is byte-identical to R2. The ONLY
// change: lin2bit is launched TWICE (idempotent: pure writes of identical
// values; same stream => serialized). dur_us(R3) - dur_us(R2) = lin2bit's
// true duration, which the top-5-by-duration counter view cannot show
// (it's hidden below the ~105us harness poison fills). This disambiguates
// "lin2bit ~30us (at roofline, stop)" vs "lin2bit ~95us (3x roofline,
// restructure weight stream for DRAM row locality next)".
__global__ __launch_bounds__(256, 4) void lin2bit_kernel(
    const int* __restrict__ wq, const float* __restrict__ scale,
    const float* __restrict__ x, float* __restrict__ ws)
{
    __shared__ unsigned short xs[BATCH][XSTR];  // 16896 B
    __shared__ int wlds[4][2][512];             // 16384 B: [wave][buf][16 rows x 32 ints]

    const int t    = threadIdx.x;
    const int lane = t & 63;
    const int wave = t >> 6;
    const int kseg = blockIdx.y * KSEG;
    const int o0   = blockIdx.x * OPB;

    // ---- weight staging geometry (swizzled source) ----
    const int srow = lane >> 3;
    const int slot = lane & 7;
    const int chnk = slot ^ srow;
    const int* g0 = wq + (size_t)(o0 + wave * 16 + srow)     * IN_K + kseg + chnk * 4;
    const int* g1 = wq + (size_t)(o0 + wave * 16 + srow + 8) * IN_K + kseg + chnk * 4;
    int* lb0 = &wlds[wave][0][0];
    int* lb1 = &wlds[wave][1][0];

#define STAGE(s) do { int* _lb = ((s) & 1) ? lb1 : lb0; \
        gll16(g0 + (s) * 32, _lb); \
        gll16(g1 + (s) * 32, _lb + 256); } while (0)

    STAGE(0);
    STAGE(1);

    // ---- stage x[0:32][kseg:+256] fp32 -> bf16 LDS ----
#pragma unroll
    for (int it = 0; it < 8; ++it) {
        int idx = it * 256 + t;
        int b   = idx >> 6;
        int k4  = idx & 63;
        float4 v = *reinterpret_cast<const float4*>(x + b * IN_K + kseg + k4 * 4);
        ushort4 h = { f2bf(v.x), f2bf(v.y), f2bf(v.z), f2bf(v.w) };
        *reinterpret_cast<ushort4*>(&xs[b][k4 * 4]) = h;
    }
    __syncthreads();   // drains vmcnt -> STAGE(0), STAGE(1) have landed

    const int quad = lane >> 4;
    const int l16  = lane & 15;
    const int o    = o0 + wave * 16 + l16;

    const unsigned short* x0 = &xs[l16][quad * 8];
    const unsigned short* x1 = &xs[l16 + 16][quad * 8];
    const int off0 = l16 * 32 + (((2 * quad)     ^ (l16 & 7)) * 4);
    const int off1 = l16 * 32 + (((2 * quad + 1) ^ (l16 & 7)) * 4);

    float4v acc0 = {0.f, 0.f, 0.f, 0.f};
    float4v acc1 = {0.f, 0.f, 0.f, 0.f};

#pragma unroll
    for (int s = 0; s < NSTEP; ++s) {
        if (s == NSTEP - 1) { asm volatile("s_waitcnt vmcnt(0)" ::: "memory"); }
        else                { asm volatile("s_waitcnt vmcnt(2)" ::: "memory"); }
        const int* wb = (s & 1) ? lb1 : lb0;
        int4v w0 = *reinterpret_cast<const int4v*>(wb + off0);
        int4v w1 = *reinterpret_cast<const int4v*>(wb + off1);
        short8 a0 = *reinterpret_cast<const short8*>(x0 + s * 32);
        short8 a1 = *reinterpret_cast<const short8*>(x1 + s * 32);
        if (s < NSTEP - 2) STAGE(s + 2);
        uint4 bw;
        bw.x = pkbf16((float)w0.y, (float)w0.x);
        bw.y = pkbf16((float)w0.w, (float)w0.z);
        bw.z = pkbf16((float)w1.y, (float)w1.x);
        bw.w = pkbf16((float)w1.w, (float)w1.z);
        short8 bf = __builtin_bit_cast(short8, bw);
        acc0 = __builtin_amdgcn_mfma_f32_16x16x32_bf16(a0, bf, acc0, 0, 0, 0);
        acc1 = __builtin_amdgcn_mfma_f32_16x16x32_bf16(a1, bf, acc1, 0, 0, 0);
    }
#undef STAGE

    // C/D layout: col(o) = lane&15, row(b) = quad*4 + reg
    const float sc = scale[o];
    const int b0 = quad * 4;
    float* __restrict__ wsp = ws + (size_t)blockIdx.y * TOT + o;
#pragma unroll
    for (int r = 0; r < 4; ++r) {
        wsp[(size_t)(b0 + r)      * OUT_N] = sc * acc0[r];
        wsp[(size_t)(b0 + r + 16) * OUT_N] = sc * acc1[r];
    }
}

// out[b][o] = bias[o] + sum_seg ws[seg][b][o]; float4-vectorized, coalesced.
__global__ __launch_bounds__(256) void reduce_kernel(
    const float* __restrict__ ws, const float* __restrict__ bias,
    float* __restrict__ out)
{
    int i4 = (blockIdx.x * 256 + threadIdx.x) * 4;
    int o  = i4 % OUT_N;
    float4v acc = *reinterpret_cast<const float4v*>(bias + o);
#pragma unroll
    for (int sgi = 0; sgi < SEGS; ++sgi) {
        float4v p = *reinterpret_cast<const float4v*>(ws + (size_t)sgi * TOT + i4);
        acc += p;
    }
    *reinterpret_cast<float4v*>(out + i4) = acc;
}

extern "C" void kernel_launch(void* const* d_in, const int* in_sizes, int n_in,
                              void* d_out, int out_size, void* d_ws, size_t ws_size,
                              hipStream_t stream) {
    const float* x     = (const float*)d_in[0];
    const int*   wq    = (const int*)d_in[1];
    const float* scale = (const float*)d_in[2];
    const float* bias  = (const float*)d_in[3];
    float* out = (float*)d_out;
    float* ws  = (float*)d_ws;   // needs SEGS*TOT*4 = 22.5 MB

    // CALIBRATION: launch twice (idempotent). Delta vs R2 = lin2bit duration.
    lin2bit_kernel<<<dim3(OUT_N / OPB, SEGS), 256, 0, stream>>>(wq, scale, x, ws);
    lin2bit_kernel<<<dim3(OUT_N / OPB, SEGS), 256, 0, stream>>>(wq, scale, x, ws);
    reduce_kernel<<<dim3(TOT / 1024), 256, 0, stream>>>(ws, bias, out);
}

// Round 4
// 251.145 us; speedup vs baseline: 1.1727x; 1.1727x over previous
//
#include <hip/hip_runtime.h>
#include <stdint.h>

#define OUT_N 11008
#define IN_K  4096
#define BATCH 32
#define SEGS  8
#define KSEG  (IN_K / SEGS)   // 512 k per block
#define NSTEP (KSEG / 32)     // 16 pipeline steps of k=32
#define OPB   64              // outputs per block (4 waves x 16 rows)
#define XSTR  520             // xs row stride (shorts): 260 dwords %32=4, same residue as verified 264
#define TOT   (BATCH * OUT_N)

typedef __attribute__((ext_vector_type(8))) short short8;
typedef __attribute__((ext_vector_type(4))) float float4v;
typedef __attribute__((ext_vector_type(4))) int int4v;

// fp32 -> bf16 RNE
__device__ __forceinline__ unsigned short f2bf(float f) {
    unsigned u = __builtin_bit_cast(unsigned, f);
    unsigned r = u + 0x7FFFu + ((u >> 16) & 1u);
    return (unsigned short)(r >> 16);
}

// pack two fp32 (exact {-1,0,1}) into two bf16 by mantissa truncation
__device__ __forceinline__ unsigned pkbf16(float fhi, float flo) {
    return __builtin_amdgcn_perm(__builtin_bit_cast(unsigned, fhi),
                                 __builtin_bit_cast(unsigned, flo),
                                 0x07060302u);
}

// async global->LDS DMA: 16 B per lane, lane L lands at lds_base + L*16.
// aux=2 = NT (no-allocate: caches are poison-dirty from the harness fill).
typedef const __attribute__((address_space(1))) int* gas_t;
typedef __attribute__((address_space(3))) int* las_t;
__device__ __forceinline__ void gll16(const int* g, int* l) {
    __builtin_amdgcn_global_load_lds((gas_t)g, (las_t)l, 16, 0, 2);
}

// R4: SEGS 16->8 (last arithmetic-backed trim). R3 calibration pinned
// lin2bit at 39.9us vs a 32.5us floor and the harness envelope at ~210us
// (two 688MiB poison fills/iter) -- total controllable headroom ~8us.
// Halving SEGS halves the ws round-trip (45->22.5MB, -3.6us), halves the
// reduce loop (-2us), halves redundant x re-reads. LDS 49.7KB -> 3 blocks/CU;
// 12 waves x 4KB DMA in flight >> 9KB BW*latency product, hiding unaffected.
// K-loop/vmcnt-ring/swizzle identical to the verified R2 template.
__global__ __launch_bounds__(256, 3) void lin2bit_kernel(
    const int* __restrict__ wq, const float* __restrict__ scale,
    const float* __restrict__ x, float* __restrict__ ws)
{
    __shared__ unsigned short xs[BATCH][XSTR];  // 33280 B
    __shared__ int wlds[4][2][512];             // 16384 B: [wave][buf][16 rows x 32 ints]

    const int t    = threadIdx.x;
    const int lane = t & 63;
    const int wave = t >> 6;
    const int kseg = blockIdx.y * KSEG;
    const int o0   = blockIdx.x * OPB;

    // ---- weight staging geometry (swizzled source) ----
    // lane L -> row (L>>3), slot (L&7); slot s holds global chunk c = s ^ (row&7)
    const int srow = lane >> 3;
    const int slot = lane & 7;
    const int chnk = slot ^ srow;
    const int* g0 = wq + (size_t)(o0 + wave * 16 + srow)     * IN_K + kseg + chnk * 4;
    const int* g1 = wq + (size_t)(o0 + wave * 16 + srow + 8) * IN_K + kseg + chnk * 4;
    int* lb0 = &wlds[wave][0][0];
    int* lb1 = &wlds[wave][1][0];

#define STAGE(s) do { int* _lb = ((s) & 1) ? lb1 : lb0; \
        gll16(g0 + (s) * 32, _lb); \
        gll16(g1 + (s) * 32, _lb + 256); } while (0)

    STAGE(0);                                   // get the HBM stream going early
    STAGE(1);

    // ---- stage x[0:32][kseg:+512] fp32 -> bf16 LDS (16 float4 per thread) ----
#pragma unroll
    for (int it = 0; it < 16; ++it) {
        int idx = it * 256 + t;
        int b   = idx >> 7;            // 128 float4 per row
        int k4  = idx & 127;
        float4 v = *reinterpret_cast<const float4*>(x + b * IN_K + kseg + k4 * 4);
        ushort4 h = { f2bf(v.x), f2bf(v.y), f2bf(v.z), f2bf(v.w) };
        *reinterpret_cast<ushort4*>(&xs[b][k4 * 4]) = h;
    }
    __syncthreads();   // drains vmcnt -> STAGE(0), STAGE(1) have landed

    const int quad = lane >> 4;
    const int l16  = lane & 15;
    const int o    = o0 + wave * 16 + l16;

    const unsigned short* x0 = &xs[l16][quad * 8];
    const unsigned short* x1 = &xs[l16 + 16][quad * 8];
    // read-side swizzle: lane wants chunks {2q, 2q+1} of row l16
    const int off0 = l16 * 32 + (((2 * quad)     ^ (l16 & 7)) * 4);
    const int off1 = l16 * 32 + (((2 * quad + 1) ^ (l16 & 7)) * 4);

    float4v acc0 = {0.f, 0.f, 0.f, 0.f};
    float4v acc1 = {0.f, 0.f, 0.f, 0.f};

#pragma unroll
    for (int s = 0; s < NSTEP; ++s) {
        // queue (oldest first): [STAGE(s), STAGE(s+1)] -> vmcnt(2) = STAGE(s) landed.
        if (s == NSTEP - 1) { asm volatile("s_waitcnt vmcnt(0)" ::: "memory"); }
        else                { asm volatile("s_waitcnt vmcnt(2)" ::: "memory"); }
        const int* wb = (s & 1) ? lb1 : lb0;
        int4v w0 = *reinterpret_cast<const int4v*>(wb + off0);   // k = s*32+q*8..+3
        int4v w1 = *reinterpret_cast<const int4v*>(wb + off1);   // k = s*32+q*8+4..+7
        short8 a0 = *reinterpret_cast<const short8*>(x0 + s * 32);
        short8 a1 = *reinterpret_cast<const short8*>(x1 + s * 32);
        if (s < NSTEP - 2) STAGE(s + 2);        // refill this parity's buffer
        uint4 bw;
        bw.x = pkbf16((float)w0.y, (float)w0.x);
        bw.y = pkbf16((float)w0.w, (float)w0.z);
        bw.z = pkbf16((float)w1.y, (float)w1.x);
        bw.w = pkbf16((float)w1.w, (float)w1.z);
        short8 bf = __builtin_bit_cast(short8, bw);
        acc0 = __builtin_amdgcn_mfma_f32_16x16x32_bf16(a0, bf, acc0, 0, 0, 0);
        acc1 = __builtin_amdgcn_mfma_f32_16x16x32_bf16(a1, bf, acc1, 0, 0, 0);
    }
#undef STAGE

    // C/D layout: col(o) = lane&15, row(b) = quad*4 + reg
    const float sc = scale[o];
    const int b0 = quad * 4;
    float* __restrict__ wsp = ws + (size_t)blockIdx.y * TOT + o;
#pragma unroll
    for (int r = 0; r < 4; ++r) {
        wsp[(size_t)(b0 + r)      * OUT_N] = sc * acc0[r];
        wsp[(size_t)(b0 + r + 16) * OUT_N] = sc * acc1[r];
    }
}

// out[b][o] = bias[o] + sum_seg ws[seg][b][o]; float4-vectorized, coalesced.
__global__ __launch_bounds__(256) void reduce_kernel(
    const float* __restrict__ ws, const float* __restrict__ bias,
    float* __restrict__ out)
{
    int i4 = (blockIdx.x * 256 + threadIdx.x) * 4;   // TOT/4 threads
    int o  = i4 % OUT_N;                             // OUT_N % 4 == 0 -> aligned
    float4v acc = *reinterpret_cast<const float4v*>(bias + o);
#pragma unroll
    for (int sgi = 0; sgi < SEGS; ++sgi) {
        float4v p = *reinterpret_cast<const float4v*>(ws + (size_t)sgi * TOT + i4);
        acc += p;
    }
    *reinterpret_cast<float4v*>(out + i4) = acc;
}

extern "C" void kernel_launch(void* const* d_in, const int* in_sizes, int n_in,
                              void* d_out, int out_size, void* d_ws, size_t ws_size,
                              hipStream_t stream) {
    const float* x     = (const float*)d_in[0];
    const int*   wq    = (const int*)d_in[1];
    const float* scale = (const float*)d_in[2];
    const float* bias  = (const float*)d_in[3];
    float* out = (float*)d_out;
    float* ws  = (float*)d_ws;   // needs SEGS*TOT*4 = 11.3 MB

    lin2bit_kernel<<<dim3(OUT_N / OPB, SEGS), 256, 0, stream>>>(wq, scale, x, ws);
    reduce_kernel<<<dim3(TOT / 1024), 256, 0, stream>>>(ws, bias, out);
}